// Round 1
// baseline (256.720 us; speedup 1.0000x reference)
//
#include <hip/hip_runtime.h>

typedef short shortx8 __attribute__((ext_vector_type(8)));
typedef float floatx4 __attribute__((ext_vector_type(4)));
typedef unsigned short ushortx4 __attribute__((ext_vector_type(4)));
typedef unsigned short ushortx8 __attribute__((ext_vector_type(8)));

typedef __attribute__((address_space(1))) char gchar;
typedef __attribute__((address_space(3))) char lchar;

__device__ __forceinline__ void async16(const void* g, void* l) {
    __builtin_amdgcn_global_load_lds((gchar*)g, (lchar*)l, 16, 0, 0);
}

__device__ __forceinline__ unsigned short f2bf(float f) {
    union { float f; unsigned int u; } v;
    v.f = f;
    unsigned int r = v.u + 0x7fffu + ((v.u >> 16) & 1u);   // RNE
    return (unsigned short)(r >> 16);
}

__device__ __forceinline__ float bf2f(unsigned short h) {
    union { unsigned int u; float f; } v;
    v.u = ((unsigned int)h) << 16;
    return v.f;
}

// ---------------------------------------------------------------------------
// 256-row 8-phase GEMM mainloop (T3+T4+T5 on top of the existing T2 swizzle).
// C[256 x 64*JN] += A[256xK] * B[(64*JN)xK]^T, bf16 in, fp32 acc.
// 512 threads = 8 waves (2M x 4N); per-wave output 128 x (16*JN).
// BK=64; LDS = 2 buffers x (A 32KB + B JN*8KB).
//
// LDS swizzle (unchanged from the verified 1282 kernel): row r holds its 8
// 16B chunks permuted by p -> p ^ xr(r), xr(r)=(r>>1)&7; staging achieves it
// with linear LDS dest + pre-swizzled per-lane GLOBAL source (both-sides rule).
// Fragment reads are 2 lanes/bank => conflict-free (measured 0 conflicts).
//
// Phase = {m-half x k-half} quadrant, 16(JN=4)/8(JN=2) MFMA each.
// Stage slots (derived from read-completion legality, 2 calls/phase):
//   computing buf0 tile T at ph1-4, buf1 tile T+1 at ph5-8:
//   ph1: A2,A4 of T+1 -> buf1      ph5: A2,A4 of T+2 -> buf0
//   ph2: B lo of T+1 -> buf1       ph6: B lo of T+2 -> buf0
//   ph3: B hi of T+1 -> buf1       ph7: B hi of T+2 -> buf0
//   ph4: A1,A3 of T+2 -> buf0      ph8: A1,A3 of T+3 -> buf1
// Single s_waitcnt vmcnt(2) at end of ph4 and ph8 (never 0 in the loop):
// outstanding = exactly that phase's 2 calls; everything older has landed,
// i.e. the next K-tile's buffer is complete. Tail stages clamp kt (harmless
// refetch) so the vmcnt accounting stays uniform.
// ---------------------------------------------------------------------------
template<int JN>   // B-fragments per wave: 4 (BN=256) or 2 (BN=128)
__device__ __forceinline__ void gemm256_mainloop(
        const ushort* __restrict__ Arow, const ushort* __restrict__ Brow,
        int K, ushort* ldsp, floatx4 (&acc)[8][JN])
{
    const int t = threadIdx.x;
    const int w = t >> 6;
    const int lane = t & 63;
    const size_t ldb = (size_t)K * 2;
    constexpr int ABYTES = 32768;
    constexpr int BBYTES = JN * 8192;
    constexpr int BUFB = ABYTES + BBYTES;
    char* l0 = (char*)ldsp;
    const int wst = w << 10;                              // per-wave stage slice
    const int sc = (((t & 7) ^ ((t >> 4) & 7)) << 4);     // pre-swizzled source chunk
    const char* gA = (const char*)Arow + (size_t)(t >> 3) * ldb + sc;
    const char* gB = (const char*)Brow + (size_t)(t >> 3) * ldb + sc;
    const int fr = lane & 15, kq = lane >> 4;
    const int xr = (fr >> 1) & 7;
    const int ck0 = (kq ^ xr) << 4;                       // k 0..31 chunk offset
    const int ck1 = ((kq + 4) ^ xr) << 4;                 // k 32..63
    const int wm = w & 1, wn = w >> 1;
    const int abase = (wm * 128 + fr) * 128;
    const int bbase = (wn * (JN * 16) + fr) * 128;

#define STA(buf, kt, R) async16(gA + (size_t)(R) * ldb + (size_t)(kt) * 128, \
                                l0 + (buf) * BUFB + (R) * 128 + wst)
#define STB(buf, kt, R) async16(gB + (size_t)(R) * ldb + (size_t)(kt) * 128, \
                                l0 + (buf) * BUFB + ABYTES + (R) * 128 + wst)
#define LDA4(buf, mb, ck)                                                          \
    a0 = *(const shortx8*)(l0 + (buf) * BUFB + abase + ((mb) + 0) * 2048 + (ck));  \
    a1 = *(const shortx8*)(l0 + (buf) * BUFB + abase + ((mb) + 1) * 2048 + (ck));  \
    a2 = *(const shortx8*)(l0 + (buf) * BUFB + abase + ((mb) + 2) * 2048 + (ck));  \
    a3 = *(const shortx8*)(l0 + (buf) * BUFB + abase + ((mb) + 3) * 2048 + (ck));
#define LDBJ(buf, ck)                                                              \
    _Pragma("unroll")                                                              \
    for (int n = 0; n < JN; ++n)                                                   \
        b[n] = *(const shortx8*)(l0 + (buf) * BUFB + ABYTES + bbase + n * 2048 + (ck));
#define PHASE_MFMA(MB)                                                             \
    __builtin_amdgcn_s_setprio(1);                                                 \
    _Pragma("unroll")                                                              \
    for (int n = 0; n < JN; ++n) {                                                 \
        acc[(MB)+0][n] = __builtin_amdgcn_mfma_f32_16x16x32_bf16(a0, b[n], acc[(MB)+0][n], 0, 0, 0); \
        acc[(MB)+1][n] = __builtin_amdgcn_mfma_f32_16x16x32_bf16(a1, b[n], acc[(MB)+1][n], 0, 0, 0); \
        acc[(MB)+2][n] = __builtin_amdgcn_mfma_f32_16x16x32_bf16(a2, b[n], acc[(MB)+2][n], 0, 0, 0); \
        acc[(MB)+3][n] = __builtin_amdgcn_mfma_f32_16x16x32_bf16(a3, b[n], acc[(MB)+3][n], 0, 0, 0); \
    }                                                                              \
    __builtin_amdgcn_s_setprio(0);
#define BAR() __builtin_amdgcn_s_barrier()
#define VMW()                                              \
    asm volatile("s_waitcnt vmcnt(2)" ::: "memory");       \
    BAR();                                                 \
    __builtin_amdgcn_sched_barrier(0);

    const int nk = K >> 6;       // K-tiles (even for all our shapes)
    const int nit = nk >> 1;

    // prologue: tile0 -> buf0 fully; tile1 A1,A3 -> buf1; wait tile0 landed.
    STA(0, 0, 0); STA(0, 0, 64); STA(0, 0, 128); STA(0, 0, 192);
    STB(0, 0, 0); STB(0, 0, 64);
    if (JN == 4) { STB(0, 0, 128); STB(0, 0, 192); }
    STA(1, 1, 0); STA(1, 1, 128);
    VMW();

    shortx8 a0, a1, a2, a3;
    shortx8 b[JN];

    for (int it = 0; it < nit; ++it) {
        const int T = 2 * it;
        int Tc2 = T + 2; if (Tc2 >= nk) Tc2 = T;        // clamped (data unused)
        int Tc3 = T + 3; if (Tc3 >= nk) Tc3 = nk - 1;

        // ph1: buf0 m0-3 k0
        LDA4(0, 0, ck0); LDBJ(0, ck0);
        STA(1, T + 1, 64); STA(1, T + 1, 192);
        BAR();
        PHASE_MFMA(0);
        BAR();

        // ph2: buf0 m4-7 k0 (b held)
        LDA4(0, 4, ck0);
        STB(1, T + 1, 0);
        if (JN == 4) STB(1, T + 1, 64);
        BAR();
        PHASE_MFMA(4);
        BAR();

        // ph3: buf0 m0-3 k1
        LDA4(0, 0, ck1); LDBJ(0, ck1);
        if (JN == 4) { STB(1, T + 1, 128); STB(1, T + 1, 192); }
        else         { STB(1, T + 1, 64); }
        BAR();
        PHASE_MFMA(0);
        BAR();

        // ph4: buf0 m4-7 k1 | K-tile boundary wait (tile T+1 complete in buf1)
        LDA4(0, 4, ck1);
        STA(0, Tc2, 0); STA(0, Tc2, 128);
        BAR();
        PHASE_MFMA(4);
        VMW();

        // ph5: buf1 m0-3 k0
        LDA4(1, 0, ck0); LDBJ(1, ck0);
        STA(0, Tc2, 64); STA(0, Tc2, 192);
        BAR();
        PHASE_MFMA(0);
        BAR();

        // ph6: buf1 m4-7 k0
        LDA4(1, 4, ck0);
        STB(0, Tc2, 0);
        if (JN == 4) STB(0, Tc2, 64);
        BAR();
        PHASE_MFMA(4);
        BAR();

        // ph7: buf1 m0-3 k1
        LDA4(1, 0, ck1); LDBJ(1, ck1);
        if (JN == 4) { STB(0, Tc2, 128); STB(0, Tc2, 192); }
        else         { STB(0, Tc2, 64); }
        BAR();
        PHASE_MFMA(0);
        BAR();

        // ph8: buf1 m4-7 k1 | K-tile boundary wait (tile T+2 complete in buf0)
        LDA4(1, 4, ck1);
        STA(1, Tc3, 0); STA(1, Tc3, 128);
        BAR();
        PHASE_MFMA(4);
        VMW();
    }
#undef STA
#undef STB
#undef LDA4
#undef LDBJ
#undef PHASE_MFMA
#undef BAR
#undef VMW
}

// ---------------------------------------------------------------------------
// QKV projection as ONE GEMM: M=8192, N=3072 (Wq|Wk|Wv rows), K=1024.
// grid (12,32): 12 N-blocks share each 256-row x-tile -> L2 reuse.
// z = nglob>>10: z=0 Q (scaled 1/32,+bq), z=1 K (+bk), z=2 V transposed.
// ---------------------------------------------------------------------------
__global__ __launch_bounds__(512, 2)
void qkv_gemm(const ushort* __restrict__ xb, const ushort* __restrict__ Wb,
              const float* __restrict__ bq, const float* __restrict__ bk,
              const float* __restrict__ bv,
              ushort* __restrict__ Qs, ushort* __restrict__ Ks,
              ushort* __restrict__ Vt) {
    __shared__ __align__(16) ushort lds[65536];   // 2 x (A 32KB | B 32KB)
    const int mbase = blockIdx.y * 256;
    const int nglob = blockIdx.x * 256;
    const int z = nglob >> 10;          // uniform per block (1024 % 256 == 0)
    const int nbase = nglob & 1023;
    floatx4 acc[8][4];
    const floatx4 zero = {0.0f, 0.0f, 0.0f, 0.0f};
#pragma unroll
    for (int i = 0; i < 8; ++i)
#pragma unroll
        for (int j = 0; j < 4; ++j) acc[i][j] = zero;

    gemm256_mainloop<4>(xb + (size_t)mbase * 1024, Wb + (size_t)nglob * 1024,
                        1024, lds, acc);

    const int t = threadIdx.x, w = t >> 6, lane = t & 63;
    const int wm = w & 1, wn = w >> 1;
    const int r0 = mbase + wm * 128 + (lane >> 4) * 4;
    const int c0 = nbase + wn * 64 + (lane & 15);
    const float* bias = (z == 0) ? bq : (z == 1) ? bk : bv;
    const float scale = (z == 0) ? 0.03125f : 1.0f;  // fold 1/sqrt(1024) into Q
    float bj[4];
#pragma unroll
    for (int j = 0; j < 4; ++j) bj[j] = bias[c0 + j * 16];

    if (z < 2) {
        ushort* O = z ? Ks : Qs;
#pragma unroll
        for (int i = 0; i < 8; ++i)
#pragma unroll
            for (int j = 0; j < 4; ++j)
#pragma unroll
                for (int r = 0; r < 4; ++r)
                    O[(size_t)(r0 + i * 16 + r) * 1024 + (c0 + j * 16)] =
                        f2bf((acc[i][j][r] + bj[j]) * scale);
    } else {
#pragma unroll
        for (int i = 0; i < 8; ++i)
#pragma unroll
            for (int j = 0; j < 4; ++j)
#pragma unroll
                for (int r = 0; r < 4; ++r) {
                    int gr = r0 + i * 16 + r;           // global row = b*2048 + s
                    int gc = c0 + j * 16;               // d
                    Vt[(size_t)(gr >> 11) * (1024 * 2048) + (size_t)gc * 2048 + (gr & 2047)] =
                        f2bf(acc[i][j][r] + bj[j]);
                }
    }
}

// ---------------------------------------------------------------------------
// Batched B^T GEMM, bf16 output (S = Q K^T). 256x256 tiles. grid.z = batch.
// ---------------------------------------------------------------------------
__global__ __launch_bounds__(512, 2)
void gemm_bt_bf16(const ushort* __restrict__ A, size_t sAz,
                  const ushort* __restrict__ B, size_t sBz,
                  ushort* __restrict__ C, size_t sCz, int N, int K) {
    __shared__ __align__(16) ushort lds[65536];
    const int mbase = blockIdx.y * 256;
    const int nbase = blockIdx.x * 256;
    const int z = blockIdx.z;
    floatx4 acc[8][4];
    const floatx4 zero = {0.0f, 0.0f, 0.0f, 0.0f};
#pragma unroll
    for (int i = 0; i < 8; ++i)
#pragma unroll
        for (int j = 0; j < 4; ++j) acc[i][j] = zero;

    gemm256_mainloop<4>(A + z * sAz + (size_t)mbase * K,
                        B + z * sBz + (size_t)nbase * K, K, lds, acc);

    const int t = threadIdx.x, w = t >> 6, lane = t & 63;
    const int wm = w & 1, wn = w >> 1;
    const int r0 = mbase + wm * 128 + (lane >> 4) * 4;
    const int c0 = nbase + wn * 64 + (lane & 15);
    ushort* Cz = C + z * sCz;
#pragma unroll
    for (int i = 0; i < 8; ++i)
#pragma unroll
        for (int j = 0; j < 4; ++j)
#pragma unroll
            for (int r = 0; r < 4; ++r)
                Cz[(size_t)(r0 + i * 16 + r) * N + (c0 + j * 16)] = f2bf(acc[i][j][r]);
}

// ---------------------------------------------------------------------------
// Batched B^T GEMM, fp32 output (O = P Vt^T). 256x128 tiles (JN=2) so the
// grid is 8x8x4 = 256 blocks (full residency at 1 block/CU). grid.z = batch.
// ---------------------------------------------------------------------------
__global__ __launch_bounds__(512, 2)
void gemm_bt_f32(const ushort* __restrict__ A, size_t sAz,
                 const ushort* __restrict__ B, size_t sBz,
                 float* __restrict__ C, size_t sCz, int N, int K) {
    __shared__ __align__(16) ushort lds[49152];   // 2 x (A 32KB | B 16KB)
    const int mbase = blockIdx.y * 256;
    const int nbase = blockIdx.x * 128;
    const int z = blockIdx.z;
    floatx4 acc[8][2];
    const floatx4 zero = {0.0f, 0.0f, 0.0f, 0.0f};
#pragma unroll
    for (int i = 0; i < 8; ++i)
#pragma unroll
        for (int j = 0; j < 2; ++j) acc[i][j] = zero;

    gemm256_mainloop<2>(A + z * sAz + (size_t)mbase * K,
                        B + z * sBz + (size_t)nbase * K, K, lds, acc);

    const int t = threadIdx.x, w = t >> 6, lane = t & 63;
    const int wm = w & 1, wn = w >> 1;
    const int r0 = mbase + wm * 128 + (lane >> 4) * 4;
    const int c0 = nbase + wn * 32 + (lane & 15);
    float* Cz = C + z * sCz;
#pragma unroll
    for (int i = 0; i < 8; ++i)
#pragma unroll
        for (int j = 0; j < 2; ++j)
#pragma unroll
            for (int r = 0; r < 4; ++r)
                Cz[(size_t)(r0 + i * 16 + r) * N + (c0 + j * 16)] = acc[i][j][r];
}

// ---------------------------------------------------------------------------
// In-place row softmax over 2048 bf16 logits. One block (256 thr) per row.
// ---------------------------------------------------------------------------
__global__ __launch_bounds__(256)
void softmax_rows_bf16(ushort* __restrict__ SP) {
    const int row = blockIdx.x;
    ushortx8* base = (ushortx8*)(SP + (size_t)row * 2048);
    const int t = threadIdx.x;
    const int w = t >> 6, lane = t & 63;
    ushortx8 v = base[t];
    float f[8];
#pragma unroll
    for (int k = 0; k < 8; ++k) f[k] = bf2f(v[k]);
    float m = f[0];
#pragma unroll
    for (int k = 1; k < 8; ++k) m = fmaxf(m, f[k]);
    for (int o = 32; o > 0; o >>= 1) m = fmaxf(m, __shfl_down(m, o));
    __shared__ float red[4];
    if (lane == 0) red[w] = m;
    __syncthreads();
    m = fmaxf(fmaxf(red[0], red[1]), fmaxf(red[2], red[3]));

    float e[8], s = 0.0f;
#pragma unroll
    for (int k = 0; k < 8; ++k) { e[k] = __expf(f[k] - m); s += e[k]; }
    for (int o = 32; o > 0; o >>= 1) s += __shfl_down(s, o);
    __syncthreads();
    if (lane == 0) red[w] = s;
    __syncthreads();
    float inv = 1.0f / (red[0] + red[1] + red[2] + red[3]);

    ushortx8 o;
#pragma unroll
    for (int k = 0; k < 8; ++k) o[k] = f2bf(e[k] * inv);
    base[t] = o;
}

// ---------------------------------------------------------------------------
// Merged fp32 -> bf16 cast for x | Wq | Wk | Wv (contiguous dst region).
// ---------------------------------------------------------------------------
__global__ __launch_bounds__(256)
void cast_bf16_all(const float* __restrict__ x, const float* __restrict__ Wq,
                   const float* __restrict__ Wk, const float* __restrict__ Wv,
                   ushort* __restrict__ dst) {
    const int NX = 2097152;   // 8192*1024/4
    const int NW = 262144;    // 1024*1024/4
    int i = blockIdx.x * 256 + threadIdx.x;
    const float* src;
    int off;
    if (i < NX)               { src = x;  off = 0; }
    else if (i < NX + NW)     { src = Wq; off = NX; }
    else if (i < NX + 2 * NW) { src = Wk; off = NX + NW; }
    else                      { src = Wv; off = NX + 2 * NW; }
    float4 v = ((const float4*)src)[i - off];
    ushortx4 o = {f2bf(v.x), f2bf(v.y), f2bf(v.z), f2bf(v.w)};
    ((ushortx4*)dst)[i] = o;
}

extern "C" void kernel_launch(void* const* d_in, const int* in_sizes, int n_in,
                              void* d_out, int out_size, void* d_ws, size_t ws_size,
                              hipStream_t stream) {
    const float* x  = (const float*)d_in[0];
    const float* bq = (const float*)d_in[2];
    const float* bk = (const float*)d_in[4];
    const float* bv = (const float*)d_in[6];
    float* out = (float*)d_out;

    const size_t R = 8192;   // B*S
    const size_t D = 1024;
    const size_t S = 2048;

    // ws layout (elems): xb R*D | Wb 3*D*D | Qs R*D | Ks R*D | Vt R*D | Sb 4*S*S(bf16)
    const size_t need = (4 * R * D + 3 * D * D + 4 * S * S) * 2;
    if (ws_size < need) return;

    ushort* xb = (ushort*)d_ws;
    ushort* Wb = xb + R * D;
    ushort* Qs = Wb + 3 * D * D;
    ushort* Ks = Qs + R * D;
    ushort* Vt = Ks + R * D;
    ushort* Sb = Vt + R * D;   // S scores, then P in place (bf16)

    cast_bf16_all<<<dim3(11264), dim3(256), 0, stream>>>(
        x, (const float*)d_in[1], (const float*)d_in[3], (const float*)d_in[5], xb);

    // QKV: one GEMM M=8192 N=3072 K=1024; 12 N-blocks share each 256-row x-tile
    qkv_gemm<<<dim3(12, 32), dim3(512), 0, stream>>>(xb, Wb, bq, bk, bv, Qs, Ks, Vt);

    // S = Qs @ K^T per batch: M=N=2048, K=1024 (scale folded into Qs), bf16 out
    gemm_bt_bf16<<<dim3(8, 8, 4), dim3(512), 0, stream>>>(Qs, S * D, Ks, S * D, Sb, S * S,
                                                          (int)S, (int)D);

    // softmax rows in place -> bf16 P
    softmax_rows_bf16<<<dim3((unsigned)(4 * S)), dim3(256), 0, stream>>>(Sb);

    // O = P @ Vt^T per batch: M=2048, N=1024, K=2048
    gemm_bt_f32<<<dim3(8, 8, 4), dim3(512), 0, stream>>>(Sb, S * S, Vt, D * S, out, S * D,
                                                         (int)D, (int)S);
}

// Round 2
// 248.842 us; speedup vs baseline: 1.0317x; 1.0317x over previous
//
#include <hip/hip_runtime.h>

typedef short shortx8 __attribute__((ext_vector_type(8)));
typedef float floatx4 __attribute__((ext_vector_type(4)));
typedef unsigned short ushortx4 __attribute__((ext_vector_type(4)));
typedef unsigned short ushortx8 __attribute__((ext_vector_type(8)));

typedef __attribute__((address_space(1))) char gchar;
typedef __attribute__((address_space(3))) char lchar;

__device__ __forceinline__ void async16(const void* g, void* l) {
    __builtin_amdgcn_global_load_lds((gchar*)g, (lchar*)l, 16, 0, 0);
}

__device__ __forceinline__ unsigned short f2bf(float f) {
    union { float f; unsigned int u; } v;
    v.f = f;
    unsigned int r = v.u + 0x7fffu + ((v.u >> 16) & 1u);   // RNE
    return (unsigned short)(r >> 16);
}

__device__ __forceinline__ float bf2f(unsigned short h) {
    union { unsigned int u; float f; } v;
    v.u = ((unsigned int)h) << 16;
    return v.f;
}

// ---------------------------------------------------------------------------
// 256-row 8-phase GEMM mainloop, fixed drain distances (round-2 rewrite).
// C[256 x 64*JN] += A[256xK] * B[(64*JN)xK]^T, bf16 in, fp32 acc.
// 512 threads = 8 waves (2M x 4N); per-wave output 128 x (16*JN). BK=64.
// LDS = 2 buffers x (A 32KB + B JN*8KB).
//
// Phase order per K-tile: (m0-3,k0) (m0-3,k1) (m4-7,k0) (m4-7,k1).
// B fragments for BOTH k-halves are read at ph1/ph2 and HELD in registers
// (b0,b1) through ph3/ph4 -> B's LDS region is free after ph2.
// A regions: {q1,q3}={rows 0-63,128-191} read ph1/ph2 (m-frags 0-3 of both
// wm waves); {q2,q4} read ph3/ph4.
//
// Stage slots, 2 global_load_lds per phase (computing T in buf0 ph1-4,
// T+1 in buf1 ph5-8):
//   ph1: A{q1,q3}(T+1)->buf1   ph5: A{q1,q3}(T+2)->buf0
//   ph2: A{q2,q4}(T+1)->buf1   ph6: A{q2,q4}(T+2)->buf0
//   ph3: B lo   (T+2)->buf0    ph7: B lo   (T+3)->buf1
//   ph4: B hi   (T+2)->buf0    ph8: B hi   (T+3)->buf1
// All slots land >=1 phase after their region's last ds_read (legal), and
// every load is >=3 phases old when drained (latency hidden).
// Waits (steady-state outstanding-set walk, uniform incl. first/last iter):
//   ph2/ph6: vmcnt(JN+4)  -- drains A{q2,q4} of current tile (4 phases old)
//   ph4/ph8: vmcnt(JN+2)  -- drains B + A{q1,q3} of next tile (3-5 phases)
// Tail iterations clamp the staged tile index (harmless refetch) so the
// vmcnt accounting stays uniform.
// ---------------------------------------------------------------------------
template<int JN>   // B-fragments per wave: 4 (BN=256), 3 (BN=192), 2 (BN=128)
__device__ __forceinline__ void gemm256_mainloop(
        const ushort* __restrict__ Arow, const ushort* __restrict__ Brow,
        int K, ushort* ldsp, floatx4 (&acc)[8][JN])
{
    const int t = threadIdx.x;
    const int w = t >> 6;
    const int lane = t & 63;
    const size_t ldb = (size_t)K * 2;
    constexpr int ABYTES = 32768;
    constexpr int BBYTES = JN * 8192;
    constexpr int BUFB = ABYTES + BBYTES;
    char* l0 = (char*)ldsp;
    const int wst = w << 10;                              // per-wave stage slice
    const int sc = (((t & 7) ^ ((t >> 4) & 7)) << 4);     // pre-swizzled src chunk
    const char* gA = (const char*)Arow + (size_t)(t >> 3) * ldb + sc;
    const char* gB = (const char*)Brow + (size_t)(t >> 3) * ldb + sc;
    const int fr = lane & 15, kq = lane >> 4;
    const int xr = (fr >> 1) & 7;
    const int ck0 = (kq ^ xr) << 4;                       // k 0..31 chunk offset
    const int ck1 = ((kq + 4) ^ xr) << 4;                 // k 32..63
    const int wm = w & 1, wn = w >> 1;
    const int abase = (wm * 128 + fr) * 128;
    const int bbase = (wn * (JN * 16) + fr) * 128;

#define STA(buf, kt, R) async16(gA + (size_t)(R) * ldb + (size_t)(kt) * 128, \
                                l0 + (buf) * BUFB + (R) * 128 + wst)
#define STB(buf, kt, R) async16(gB + (size_t)(R) * ldb + (size_t)(kt) * 128, \
                                l0 + (buf) * BUFB + ABYTES + (R) * 128 + wst)
#define LDA4(buf, mb, ck)                                                          \
    a0 = *(const shortx8*)(l0 + (buf) * BUFB + abase + ((mb) + 0) * 2048 + (ck));  \
    a1 = *(const shortx8*)(l0 + (buf) * BUFB + abase + ((mb) + 1) * 2048 + (ck));  \
    a2 = *(const shortx8*)(l0 + (buf) * BUFB + abase + ((mb) + 2) * 2048 + (ck));  \
    a3 = *(const shortx8*)(l0 + (buf) * BUFB + abase + ((mb) + 3) * 2048 + (ck));
#define LDB(buf, ck, dst)                                                          \
    _Pragma("unroll")                                                              \
    for (int n = 0; n < JN; ++n)                                                   \
        dst[n] = *(const shortx8*)(l0 + (buf) * BUFB + ABYTES + bbase + n * 2048 + (ck));
#define PH(MB, BV)                                                                 \
    __builtin_amdgcn_s_setprio(1);                                                 \
    _Pragma("unroll")                                                              \
    for (int n = 0; n < JN; ++n) {                                                 \
        acc[(MB) + 0][n] = __builtin_amdgcn_mfma_f32_16x16x32_bf16(a0, BV[n], acc[(MB) + 0][n], 0, 0, 0); \
        acc[(MB) + 1][n] = __builtin_amdgcn_mfma_f32_16x16x32_bf16(a1, BV[n], acc[(MB) + 1][n], 0, 0, 0); \
        acc[(MB) + 2][n] = __builtin_amdgcn_mfma_f32_16x16x32_bf16(a2, BV[n], acc[(MB) + 2][n], 0, 0, 0); \
        acc[(MB) + 3][n] = __builtin_amdgcn_mfma_f32_16x16x32_bf16(a3, BV[n], acc[(MB) + 3][n], 0, 0, 0); \
    }                                                                              \
    __builtin_amdgcn_s_setprio(0);
#define BAR() __builtin_amdgcn_s_barrier()
#define VMW_A()                                                        \
    asm volatile("s_waitcnt vmcnt(%0)" :: "i"(JN + 4) : "memory");     \
    __builtin_amdgcn_s_barrier();                                      \
    __builtin_amdgcn_sched_barrier(0);
#define VMW_B()                                                        \
    asm volatile("s_waitcnt vmcnt(%0)" :: "i"(JN + 2) : "memory");     \
    __builtin_amdgcn_s_barrier();                                      \
    __builtin_amdgcn_sched_barrier(0);

    const int nk = K >> 6;       // K-tiles (even for all our shapes)
    const int nit = nk >> 1;

    // Prologue. Issue order matters for the vmcnt drain sets:
    //   [A q1,q3 (0)] [B(0)] [A q2,q4 (0)] [B(1)] ; vmcnt(JN+2)
    // leaves {A q2,q4(0), B(1)} outstanding = the steady-state entry set.
    STA(0, 0, 0); STA(0, 0, 128);
    STB(0, 0, 0); STB(0, 0, 64);
    if (JN >= 3) STB(0, 0, 128);
    if (JN == 4) STB(0, 0, 192);
    STA(0, 0, 64); STA(0, 0, 192);
    STB(1, 1, 0); STB(1, 1, 64);
    if (JN >= 3) STB(1, 1, 128);
    if (JN == 4) STB(1, 1, 192);
    asm volatile("s_waitcnt vmcnt(%0)" :: "i"(JN + 2) : "memory");
    BAR();
    __builtin_amdgcn_sched_barrier(0);

    shortx8 a0, a1, a2, a3;
    shortx8 b0[JN], b1[JN];

    for (int it = 0; it < nit; ++it) {
        const int T = 2 * it;
        const int T1 = T + 1;
        int T2 = T + 2; if (T2 > nk - 1) T2 = nk - 1;   // clamped (data unused)
        int T3 = T + 3; if (T3 > nk - 1) T3 = nk - 1;

        // ph1: buf0 m0-3 k0 | stage A{q1,q3}(T+1)->buf1
        LDA4(0, 0, ck0); LDB(0, ck0, b0);
        STA(1, T1, 0); STA(1, T1, 128);
        BAR();
        PH(0, b0);
        BAR();

        // ph2: buf0 m0-3 k1 | stage A{q2,q4}(T+1)->buf1
        LDA4(0, 0, ck1); LDB(0, ck1, b1);
        STA(1, T1, 64); STA(1, T1, 192);
        BAR();
        PH(0, b1);
        VMW_A();

        // ph3: buf0 m4-7 k0 (b0 held) | stage B-lo(T+2)->buf0
        LDA4(0, 4, ck0);
        STB(0, T2, 0); STB(0, T2, 64);
        BAR();
        PH(4, b0);
        BAR();

        // ph4: buf0 m4-7 k1 (b1 held) | stage B-hi(T+2)->buf0
        LDA4(0, 4, ck1);
        if (JN >= 3) STB(0, T2, 128);
        if (JN == 4) STB(0, T2, 192);
        BAR();
        PH(4, b1);
        VMW_B();

        // ph5: buf1 m0-3 k0 | stage A{q1,q3}(T+2)->buf0
        LDA4(1, 0, ck0); LDB(1, ck0, b0);
        STA(0, T2, 0); STA(0, T2, 128);
        BAR();
        PH(0, b0);
        BAR();

        // ph6: buf1 m0-3 k1 | stage A{q2,q4}(T+2)->buf0
        LDA4(1, 0, ck1); LDB(1, ck1, b1);
        STA(0, T2, 64); STA(0, T2, 192);
        BAR();
        PH(0, b1);
        VMW_A();

        // ph7: buf1 m4-7 k0 | stage B-lo(T+3)->buf1
        LDA4(1, 4, ck0);
        STB(1, T3, 0); STB(1, T3, 64);
        BAR();
        PH(4, b0);
        BAR();

        // ph8: buf1 m4-7 k1 | stage B-hi(T+3)->buf1
        LDA4(1, 4, ck1);
        if (JN >= 3) STB(1, T3, 128);
        if (JN == 4) STB(1, T3, 192);
        BAR();
        PH(4, b1);
        VMW_B();
    }
#undef STA
#undef STB
#undef LDA4
#undef LDB
#undef PH
#undef BAR
#undef VMW_A
#undef VMW_B
}

// ---------------------------------------------------------------------------
// QKV projection as ONE GEMM: M=8192, N=3072 (Wq|Wk|Wv rows), K=1024.
// BN=192 (JN=3) -> grid (16,32) = 512 blocks = exactly 2 full-residency
// rounds at 1 block/CU (eliminates the 1.5-round tail of BN=256).
// Tiles cross the Q|K|V boundary, but every 16-wide fragment stays inside
// one projection (1024 % 16 == 0) -> z is wave-uniform per fragment.
// ---------------------------------------------------------------------------
__global__ __launch_bounds__(512, 2)
void qkv_gemm(const ushort* __restrict__ xb, const ushort* __restrict__ Wb,
              const float* __restrict__ bq, const float* __restrict__ bk,
              const float* __restrict__ bv,
              ushort* __restrict__ Qs, ushort* __restrict__ Ks,
              ushort* __restrict__ Vt) {
    __shared__ __align__(16) ushort lds[57344];   // 2 x (A 32KB | B 24KB) = 112KB
    const int mbase = blockIdx.y * 256;
    const int nglob = blockIdx.x * 192;
    floatx4 acc[8][3];
    const floatx4 zero = {0.0f, 0.0f, 0.0f, 0.0f};
#pragma unroll
    for (int i = 0; i < 8; ++i)
#pragma unroll
        for (int j = 0; j < 3; ++j) acc[i][j] = zero;

    gemm256_mainloop<3>(xb + (size_t)mbase * 1024, Wb + (size_t)nglob * 1024,
                        1024, lds, acc);

    const int t = threadIdx.x, w = t >> 6, lane = t & 63;
    const int wm = w & 1, wn = w >> 1;
    const int r0 = mbase + wm * 128 + (lane >> 4) * 4;
#pragma unroll
    for (int j = 0; j < 3; ++j) {
        const int cj = nglob + wn * 48 + j * 16;   // fragment base col (wave-uniform)
        const int z = cj >> 10;                    // 0=Q 1=K 2=V
        const int gc = (cj & 1023) + (lane & 15);  // col within projection
        const float* bias = (z == 0) ? bq : (z == 1) ? bk : bv;
        const float bj = bias[gc];
        if (z == 0) {
#pragma unroll
            for (int i = 0; i < 8; ++i)
#pragma unroll
                for (int r = 0; r < 4; ++r)
                    Qs[(size_t)(r0 + i * 16 + r) * 1024 + gc] =
                        f2bf((acc[i][j][r] + bj) * 0.03125f);   // fold 1/sqrt(1024)
        } else if (z == 1) {
#pragma unroll
            for (int i = 0; i < 8; ++i)
#pragma unroll
                for (int r = 0; r < 4; ++r)
                    Ks[(size_t)(r0 + i * 16 + r) * 1024 + gc] = f2bf(acc[i][j][r] + bj);
        } else {
#pragma unroll
            for (int i = 0; i < 8; ++i)
#pragma unroll
                for (int r = 0; r < 4; ++r) {
                    int gr = r0 + i * 16 + r;      // global row = b*2048 + s
                    Vt[(size_t)(gr >> 11) * (1024 * 2048) + (size_t)gc * 2048 + (gr & 2047)] =
                        f2bf(acc[i][j][r] + bj);
                }
        }
    }
}

// ---------------------------------------------------------------------------
// Batched B^T GEMM, bf16 output (S = Q K^T). 256x256 tiles. grid (8,8,4)=256
// blocks = perfect single-round residency. grid.z = batch.
// ---------------------------------------------------------------------------
__global__ __launch_bounds__(512, 2)
void gemm_bt_bf16(const ushort* __restrict__ A, size_t sAz,
                  const ushort* __restrict__ B, size_t sBz,
                  ushort* __restrict__ C, size_t sCz, int N, int K) {
    __shared__ __align__(16) ushort lds[65536];   // 128KB
    const int mbase = blockIdx.y * 256;
    const int nbase = blockIdx.x * 256;
    const int z = blockIdx.z;
    floatx4 acc[8][4];
    const floatx4 zero = {0.0f, 0.0f, 0.0f, 0.0f};
#pragma unroll
    for (int i = 0; i < 8; ++i)
#pragma unroll
        for (int j = 0; j < 4; ++j) acc[i][j] = zero;

    gemm256_mainloop<4>(A + z * sAz + (size_t)mbase * K,
                        B + z * sBz + (size_t)nbase * K, K, lds, acc);

    const int t = threadIdx.x, w = t >> 6, lane = t & 63;
    const int wm = w & 1, wn = w >> 1;
    const int r0 = mbase + wm * 128 + (lane >> 4) * 4;
    const int c0 = nbase + wn * 64 + (lane & 15);
    ushort* Cz = C + z * sCz;
#pragma unroll
    for (int i = 0; i < 8; ++i)
#pragma unroll
        for (int j = 0; j < 4; ++j)
#pragma unroll
            for (int r = 0; r < 4; ++r)
                Cz[(size_t)(r0 + i * 16 + r) * N + (c0 + j * 16)] = f2bf(acc[i][j][r]);
}

// ---------------------------------------------------------------------------
// Batched B^T GEMM, fp32 output (O = P Vt^T). 256x128 tiles (JN=2) -> grid
// (8,8,4) = 256 blocks, full residency. grid.z = batch.
// ---------------------------------------------------------------------------
__global__ __launch_bounds__(512, 2)
void gemm_bt_f32(const ushort* __restrict__ A, size_t sAz,
                 const ushort* __restrict__ B, size_t sBz,
                 float* __restrict__ C, size_t sCz, int N, int K) {
    __shared__ __align__(16) ushort lds[49152];   // 2 x (A 32KB | B 16KB) = 96KB
    const int mbase = blockIdx.y * 256;
    const int nbase = blockIdx.x * 128;
    const int z = blockIdx.z;
    floatx4 acc[8][2];
    const floatx4 zero = {0.0f, 0.0f, 0.0f, 0.0f};
#pragma unroll
    for (int i = 0; i < 8; ++i)
#pragma unroll
        for (int j = 0; j < 2; ++j) acc[i][j] = zero;

    gemm256_mainloop<2>(A + z * sAz + (size_t)mbase * K,
                        B + z * sBz + (size_t)nbase * K, K, lds, acc);

    const int t = threadIdx.x, w = t >> 6, lane = t & 63;
    const int wm = w & 1, wn = w >> 1;
    const int r0 = mbase + wm * 128 + (lane >> 4) * 4;
    const int c0 = nbase + wn * 32 + (lane & 15);
    float* Cz = C + z * sCz;
#pragma unroll
    for (int i = 0; i < 8; ++i)
#pragma unroll
        for (int j = 0; j < 2; ++j)
#pragma unroll
            for (int r = 0; r < 4; ++r)
                Cz[(size_t)(r0 + i * 16 + r) * N + (c0 + j * 16)] = acc[i][j][r];
}

// ---------------------------------------------------------------------------
// In-place row softmax over 2048 bf16 logits. One block (256 thr) per row.
// ---------------------------------------------------------------------------
__global__ __launch_bounds__(256)
void softmax_rows_bf16(ushort* __restrict__ SP) {
    const int row = blockIdx.x;
    ushortx8* base = (ushortx8*)(SP + (size_t)row * 2048);
    const int t = threadIdx.x;
    const int w = t >> 6, lane = t & 63;
    ushortx8 v = base[t];
    float f[8];
#pragma unroll
    for (int k = 0; k < 8; ++k) f[k] = bf2f(v[k]);
    float m = f[0];
#pragma unroll
    for (int k = 1; k < 8; ++k) m = fmaxf(m, f[k]);
    for (int o = 32; o > 0; o >>= 1) m = fmaxf(m, __shfl_down(m, o));
    __shared__ float red[4];
    if (lane == 0) red[w] = m;
    __syncthreads();
    m = fmaxf(fmaxf(red[0], red[1]), fmaxf(red[2], red[3]));

    float e[8], s = 0.0f;
#pragma unroll
    for (int k = 0; k < 8; ++k) { e[k] = __expf(f[k] - m); s += e[k]; }
    for (int o = 32; o > 0; o >>= 1) s += __shfl_down(s, o);
    __syncthreads();
    if (lane == 0) red[w] = s;
    __syncthreads();
    float inv = 1.0f / (red[0] + red[1] + red[2] + red[3]);

    ushortx8 o;
#pragma unroll
    for (int k = 0; k < 8; ++k) o[k] = f2bf(e[k] * inv);
    base[t] = o;
}

// ---------------------------------------------------------------------------
// Merged fp32 -> bf16 cast for x | Wq | Wk | Wv (contiguous dst region).
// ---------------------------------------------------------------------------
__global__ __launch_bounds__(256)
void cast_bf16_all(const float* __restrict__ x, const float* __restrict__ Wq,
                   const float* __restrict__ Wk, const float* __restrict__ Wv,
                   ushort* __restrict__ dst) {
    const int NX = 2097152;   // 8192*1024/4
    const int NW = 262144;    // 1024*1024/4
    int i = blockIdx.x * 256 + threadIdx.x;
    const float* src;
    int off;
    if (i < NX)               { src = x;  off = 0; }
    else if (i < NX + NW)     { src = Wq; off = NX; }
    else if (i < NX + 2 * NW) { src = Wk; off = NX + NW; }
    else                      { src = Wv; off = NX + 2 * NW; }
    float4 v = ((const float4*)src)[i - off];
    ushortx4 o = {f2bf(v.x), f2bf(v.y), f2bf(v.z), f2bf(v.w)};
    ((ushortx4*)dst)[i] = o;
}

extern "C" void kernel_launch(void* const* d_in, const int* in_sizes, int n_in,
                              void* d_out, int out_size, void* d_ws, size_t ws_size,
                              hipStream_t stream) {
    const float* x  = (const float*)d_in[0];
    const float* bq = (const float*)d_in[2];
    const float* bk = (const float*)d_in[4];
    const float* bv = (const float*)d_in[6];
    float* out = (float*)d_out;

    const size_t R = 8192;   // B*S
    const size_t D = 1024;
    const size_t S = 2048;

    // ws layout (elems): xb R*D | Wb 3*D*D | Qs R*D | Ks R*D | Vt R*D | Sb 4*S*S(bf16)
    const size_t need = (4 * R * D + 3 * D * D + 4 * S * S) * 2;
    if (ws_size < need) return;

    ushort* xb = (ushort*)d_ws;
    ushort* Wb = xb + R * D;
    ushort* Qs = Wb + 3 * D * D;
    ushort* Ks = Qs + R * D;
    ushort* Vt = Ks + R * D;
    ushort* Sb = Vt + R * D;   // S scores, then P in place (bf16)

    cast_bf16_all<<<dim3(11264), dim3(256), 0, stream>>>(
        x, (const float*)d_in[1], (const float*)d_in[3], (const float*)d_in[5], xb);

    // QKV: one GEMM M=8192 N=3072 K=1024; BN=192 -> 512 blocks = 2 full rounds
    qkv_gemm<<<dim3(16, 32), dim3(512), 0, stream>>>(xb, Wb, bq, bk, bv, Qs, Ks, Vt);

    // S = Qs @ K^T per batch: M=N=2048, K=1024 (scale folded into Qs), bf16 out
    gemm_bt_bf16<<<dim3(8, 8, 4), dim3(512), 0, stream>>>(Qs, S * D, Ks, S * D, Sb, S * S,
                                                          (int)S, (int)D);

    // softmax rows in place -> bf16 P
    softmax_rows_bf16<<<dim3((unsigned)(4 * S)), dim3(256), 0, stream>>>(Sb);

    // O = P @ Vt^T per batch: M=2048, N=1024, K=2048
    gemm_bt_f32<<<dim3(8, 8, 4), dim3(512), 0, stream>>>(Sb, S * S, Vt, D * S, out, S * D,
                                                         (int)D, (int)S);
}

// Round 3
// 246.715 us; speedup vs baseline: 1.0405x; 1.0086x over previous
//
#include <hip/hip_runtime.h>

typedef short shortx8 __attribute__((ext_vector_type(8)));
typedef float floatx4 __attribute__((ext_vector_type(4)));
typedef unsigned short ushortx4 __attribute__((ext_vector_type(4)));
typedef unsigned short ushortx8 __attribute__((ext_vector_type(8)));

typedef __attribute__((address_space(1))) char gchar;
typedef __attribute__((address_space(3))) char lchar;

__device__ __forceinline__ void async16(const void* g, void* l) {
    __builtin_amdgcn_global_load_lds((gchar*)g, (lchar*)l, 16, 0, 0);
}

__device__ __forceinline__ unsigned short f2bf(float f) {
    union { float f; unsigned int u; } v;
    v.f = f;
    unsigned int r = v.u + 0x7fffu + ((v.u >> 16) & 1u);   // RNE
    return (unsigned short)(r >> 16);
}

__device__ __forceinline__ float bf2f(unsigned short h) {
    union { unsigned int u; float f; } v;
    v.u = ((unsigned int)h) << 16;
    return v.f;
}

// ---------------------------------------------------------------------------
// 256-row 8-phase GEMM mainloop. Round-3 change: explicit scheduling fences
// per phase (the element of the m201 template omitted in rounds 1-2):
//   [ds_reads + stages]            <- issued EARLY, pinned by fence below
//   sched_barrier(0)               <- loads cannot sink past here
//   s_barrier
//   s_waitcnt lgkmcnt(0) (asm)     <- own ds_reads done (cheap: issued early)
//   sched_barrier(0)               <- rule #18: MFMAs cannot hoist above
//   setprio(1); MFMA cluster; setprio(0)
//   s_barrier
// Without the fences the compiler sinks ds_read issues to first MFMA use /
// hoists MFMAs above waits, collapsing the issue-early overlap (observed:
// MfmaUtil 31% vs m201's 62% with identical source-level structure).
//
// Geometry/waits unchanged from round 2 (verified by outstanding-set walk):
// phase order (m0-3,k0)(m0-3,k1)(m4-7,k0)(m4-7,k1); B both k-halves held in
// regs (b0,b1); stage slots 2/phase; waits vmcnt(JN+4) at ph2/ph6,
// vmcnt(JN+2) at ph4/ph8 (every drained load >=3 phases old).
// ---------------------------------------------------------------------------
template<int JN>   // B-fragments per wave: 4 (BN=256), 3 (BN=192), 2 (BN=128)
__device__ __forceinline__ void gemm256_mainloop(
        const ushort* __restrict__ Arow, const ushort* __restrict__ Brow,
        int K, ushort* ldsp, floatx4 (&acc)[8][JN])
{
    const int t = threadIdx.x;
    const int w = t >> 6;
    const int lane = t & 63;
    const size_t ldb = (size_t)K * 2;
    constexpr int ABYTES = 32768;
    constexpr int BBYTES = JN * 8192;
    constexpr int BUFB = ABYTES + BBYTES;
    char* l0 = (char*)ldsp;
    const int wst = w << 10;                              // per-wave stage slice
    const int sc = (((t & 7) ^ ((t >> 4) & 7)) << 4);     // pre-swizzled src chunk
    const char* gA = (const char*)Arow + (size_t)(t >> 3) * ldb + sc;
    const char* gB = (const char*)Brow + (size_t)(t >> 3) * ldb + sc;
    const int fr = lane & 15, kq = lane >> 4;
    const int xr = (fr >> 1) & 7;
    const int ck0 = (kq ^ xr) << 4;                       // k 0..31 chunk offset
    const int ck1 = ((kq + 4) ^ xr) << 4;                 // k 32..63
    const int wm = w & 1, wn = w >> 1;
    const int abase = (wm * 128 + fr) * 128;
    const int bbase = (wn * (JN * 16) + fr) * 128;

#define STA(buf, kt, R) async16(gA + (size_t)(R) * ldb + (size_t)(kt) * 128, \
                                l0 + (buf) * BUFB + (R) * 128 + wst)
#define STB(buf, kt, R) async16(gB + (size_t)(R) * ldb + (size_t)(kt) * 128, \
                                l0 + (buf) * BUFB + ABYTES + (R) * 128 + wst)
#define LDA4(buf, mb, ck)                                                          \
    a0 = *(const shortx8*)(l0 + (buf) * BUFB + abase + ((mb) + 0) * 2048 + (ck));  \
    a1 = *(const shortx8*)(l0 + (buf) * BUFB + abase + ((mb) + 1) * 2048 + (ck));  \
    a2 = *(const shortx8*)(l0 + (buf) * BUFB + abase + ((mb) + 2) * 2048 + (ck));  \
    a3 = *(const shortx8*)(l0 + (buf) * BUFB + abase + ((mb) + 3) * 2048 + (ck));
#define LDB(buf, ck, dst)                                                          \
    _Pragma("unroll")                                                              \
    for (int n = 0; n < JN; ++n)                                                   \
        dst[n] = *(const shortx8*)(l0 + (buf) * BUFB + ABYTES + bbase + n * 2048 + (ck));
#define PH(MB, BV)                                                                 \
    __builtin_amdgcn_s_setprio(1);                                                 \
    _Pragma("unroll")                                                              \
    for (int n = 0; n < JN; ++n) {                                                 \
        acc[(MB) + 0][n] = __builtin_amdgcn_mfma_f32_16x16x32_bf16(a0, BV[n], acc[(MB) + 0][n], 0, 0, 0); \
        acc[(MB) + 1][n] = __builtin_amdgcn_mfma_f32_16x16x32_bf16(a1, BV[n], acc[(MB) + 1][n], 0, 0, 0); \
        acc[(MB) + 2][n] = __builtin_amdgcn_mfma_f32_16x16x32_bf16(a2, BV[n], acc[(MB) + 2][n], 0, 0, 0); \
        acc[(MB) + 3][n] = __builtin_amdgcn_mfma_f32_16x16x32_bf16(a3, BV[n], acc[(MB) + 3][n], 0, 0, 0); \
    }                                                                              \
    __builtin_amdgcn_s_setprio(0);
// Phase-open: pin loads above, MFMAs below (rule #18 + m201 template order).
#define PH_OPEN()                                                      \
    __builtin_amdgcn_sched_barrier(0);                                 \
    __builtin_amdgcn_s_barrier();                                      \
    asm volatile("s_waitcnt lgkmcnt(0)" ::: "memory");                 \
    __builtin_amdgcn_sched_barrier(0);
#define PH_CLOSE() __builtin_amdgcn_s_barrier();
#define VMW_A()                                                        \
    asm volatile("s_waitcnt vmcnt(%0)" :: "i"(JN + 4) : "memory");     \
    __builtin_amdgcn_s_barrier();                                      \
    __builtin_amdgcn_sched_barrier(0);
#define VMW_B()                                                        \
    asm volatile("s_waitcnt vmcnt(%0)" :: "i"(JN + 2) : "memory");     \
    __builtin_amdgcn_s_barrier();                                      \
    __builtin_amdgcn_sched_barrier(0);

    const int nk = K >> 6;       // K-tiles (even for all our shapes)
    const int nit = nk >> 1;

    // Prologue. Issue order matters for the vmcnt drain sets:
    //   [A q1,q3 (0)] [B(0)] [A q2,q4 (0)] [B(1)] ; vmcnt(JN+2)
    // leaves {A q2,q4(0), B(1)} outstanding = the steady-state entry set.
    STA(0, 0, 0); STA(0, 0, 128);
    STB(0, 0, 0); STB(0, 0, 64);
    if (JN >= 3) STB(0, 0, 128);
    if (JN == 4) STB(0, 0, 192);
    STA(0, 0, 64); STA(0, 0, 192);
    STB(1, 1, 0); STB(1, 1, 64);
    if (JN >= 3) STB(1, 1, 128);
    if (JN == 4) STB(1, 1, 192);
    asm volatile("s_waitcnt vmcnt(%0)" :: "i"(JN + 2) : "memory");
    __builtin_amdgcn_s_barrier();
    __builtin_amdgcn_sched_barrier(0);

    shortx8 a0, a1, a2, a3;
    shortx8 b0[JN], b1[JN];

    for (int it = 0; it < nit; ++it) {
        const int T = 2 * it;
        const int T1 = T + 1;
        int T2 = T + 2; if (T2 > nk - 1) T2 = nk - 1;   // clamped (data unused)
        int T3 = T + 3; if (T3 > nk - 1) T3 = nk - 1;

        // ph1: buf0 m0-3 k0 | stage A{q1,q3}(T+1)->buf1
        LDA4(0, 0, ck0); LDB(0, ck0, b0);
        STA(1, T1, 0); STA(1, T1, 128);
        PH_OPEN();
        PH(0, b0);
        PH_CLOSE();

        // ph2: buf0 m0-3 k1 | stage A{q2,q4}(T+1)->buf1
        LDA4(0, 0, ck1); LDB(0, ck1, b1);
        STA(1, T1, 64); STA(1, T1, 192);
        PH_OPEN();
        PH(0, b1);
        VMW_A();

        // ph3: buf0 m4-7 k0 (b0 held) | stage B-lo(T+2)->buf0
        LDA4(0, 4, ck0);
        STB(0, T2, 0); STB(0, T2, 64);
        PH_OPEN();
        PH(4, b0);
        PH_CLOSE();

        // ph4: buf0 m4-7 k1 (b1 held) | stage B-hi(T+2)->buf0
        LDA4(0, 4, ck1);
        if (JN >= 3) STB(0, T2, 128);
        if (JN == 4) STB(0, T2, 192);
        PH_OPEN();
        PH(4, b1);
        VMW_B();

        // ph5: buf1 m0-3 k0 | stage A{q1,q3}(T+2)->buf0
        LDA4(1, 0, ck0); LDB(1, ck0, b0);
        STA(0, T2, 0); STA(0, T2, 128);
        PH_OPEN();
        PH(0, b0);
        PH_CLOSE();

        // ph6: buf1 m0-3 k1 | stage A{q2,q4}(T+2)->buf0
        LDA4(1, 0, ck1); LDB(1, ck1, b1);
        STA(0, T2, 64); STA(0, T2, 192);
        PH_OPEN();
        PH(0, b1);
        VMW_A();

        // ph7: buf1 m4-7 k0 | stage B-lo(T+3)->buf1
        LDA4(1, 4, ck0);
        STB(1, T3, 0); STB(1, T3, 64);
        PH_OPEN();
        PH(4, b0);
        PH_CLOSE();

        // ph8: buf1 m4-7 k1 | stage B-hi(T+3)->buf1
        LDA4(1, 4, ck1);
        if (JN >= 3) STB(1, T3, 128);
        if (JN == 4) STB(1, T3, 192);
        PH_OPEN();
        PH(4, b1);
        VMW_B();
    }
#undef STA
#undef STB
#undef LDA4
#undef LDB
#undef PH
#undef PH_OPEN
#undef PH_CLOSE
#undef VMW_A
#undef VMW_B
}

// ---------------------------------------------------------------------------
// QKV projection as ONE GEMM: M=8192, N=3072 (Wq|Wk|Wv rows), K=1024.
// BN=192 (JN=3) -> grid (16,32) = 512 blocks = exactly 2 full-residency
// rounds at 1 block/CU. Fragments never cross a projection boundary
// (1024 % 16 == 0) -> z is wave-uniform per fragment.
// ---------------------------------------------------------------------------
__global__ __launch_bounds__(512, 2)
void qkv_gemm(const ushort* __restrict__ xb, const ushort* __restrict__ Wb,
              const float* __restrict__ bq, const float* __restrict__ bk,
              const float* __restrict__ bv,
              ushort* __restrict__ Qs, ushort* __restrict__ Ks,
              ushort* __restrict__ Vt) {
    __shared__ __align__(16) ushort lds[57344];   // 2 x (A 32KB | B 24KB) = 112KB
    const int mbase = blockIdx.y * 256;
    const int nglob = blockIdx.x * 192;
    floatx4 acc[8][3];
    const floatx4 zero = {0.0f, 0.0f, 0.0f, 0.0f};
#pragma unroll
    for (int i = 0; i < 8; ++i)
#pragma unroll
        for (int j = 0; j < 3; ++j) acc[i][j] = zero;

    gemm256_mainloop<3>(xb + (size_t)mbase * 1024, Wb + (size_t)nglob * 1024,
                        1024, lds, acc);

    const int t = threadIdx.x, w = t >> 6, lane = t & 63;
    const int wm = w & 1, wn = w >> 1;
    const int r0 = mbase + wm * 128 + (lane >> 4) * 4;
#pragma unroll
    for (int j = 0; j < 3; ++j) {
        const int cj = nglob + wn * 48 + j * 16;   // fragment base col (wave-uniform)
        const int z = cj >> 10;                    // 0=Q 1=K 2=V
        const int gc = (cj & 1023) + (lane & 15);  // col within projection
        const float* bias = (z == 0) ? bq : (z == 1) ? bk : bv;
        const float bj = bias[gc];
        if (z == 0) {
#pragma unroll
            for (int i = 0; i < 8; ++i)
#pragma unroll
                for (int r = 0; r < 4; ++r)
                    Qs[(size_t)(r0 + i * 16 + r) * 1024 + gc] =
                        f2bf((acc[i][j][r] + bj) * 0.03125f);   // fold 1/sqrt(1024)
        } else if (z == 1) {
#pragma unroll
            for (int i = 0; i < 8; ++i)
#pragma unroll
                for (int r = 0; r < 4; ++r)
                    Ks[(size_t)(r0 + i * 16 + r) * 1024 + gc] = f2bf(acc[i][j][r] + bj);
        } else {
#pragma unroll
            for (int i = 0; i < 8; ++i)
#pragma unroll
                for (int r = 0; r < 4; ++r) {
                    int gr = r0 + i * 16 + r;      // global row = b*2048 + s
                    Vt[(size_t)(gr >> 11) * (1024 * 2048) + (size_t)gc * 2048 + (gr & 2047)] =
                        f2bf(acc[i][j][r] + bj);
                }
        }
    }
}

// ---------------------------------------------------------------------------
// Batched B^T GEMM, bf16 output (S = Q K^T). 256x256 tiles. grid (8,8,4)=256
// blocks = perfect single-round residency. grid.z = batch.
// ---------------------------------------------------------------------------
__global__ __launch_bounds__(512, 2)
void gemm_bt_bf16(const ushort* __restrict__ A, size_t sAz,
                  const ushort* __restrict__ B, size_t sBz,
                  ushort* __restrict__ C, size_t sCz, int N, int K) {
    __shared__ __align__(16) ushort lds[65536];   // 128KB
    const int mbase = blockIdx.y * 256;
    const int nbase = blockIdx.x * 256;
    const int z = blockIdx.z;
    floatx4 acc[8][4];
    const floatx4 zero = {0.0f, 0.0f, 0.0f, 0.0f};
#pragma unroll
    for (int i = 0; i < 8; ++i)
#pragma unroll
        for (int j = 0; j < 4; ++j) acc[i][j] = zero;

    gemm256_mainloop<4>(A + z * sAz + (size_t)mbase * K,
                        B + z * sBz + (size_t)nbase * K, K, lds, acc);

    const int t = threadIdx.x, w = t >> 6, lane = t & 63;
    const int wm = w & 1, wn = w >> 1;
    const int r0 = mbase + wm * 128 + (lane >> 4) * 4;
    const int c0 = nbase + wn * 64 + (lane & 15);
    ushort* Cz = C + z * sCz;
#pragma unroll
    for (int i = 0; i < 8; ++i)
#pragma unroll
        for (int j = 0; j < 4; ++j)
#pragma unroll
            for (int r = 0; r < 4; ++r)
                Cz[(size_t)(r0 + i * 16 + r) * N + (c0 + j * 16)] = f2bf(acc[i][j][r]);
}

// ---------------------------------------------------------------------------
// Batched B^T GEMM, fp32 output (O = P Vt^T). 256x128 tiles (JN=2) -> grid
// (8,8,4) = 256 blocks, full residency. grid.z = batch.
// ---------------------------------------------------------------------------
__global__ __launch_bounds__(512, 2)
void gemm_bt_f32(const ushort* __restrict__ A, size_t sAz,
                 const ushort* __restrict__ B, size_t sBz,
                 float* __restrict__ C, size_t sCz, int N, int K) {
    __shared__ __align__(16) ushort lds[49152];   // 2 x (A 32KB | B 16KB) = 96KB
    const int mbase = blockIdx.y * 256;
    const int nbase = blockIdx.x * 128;
    const int z = blockIdx.z;
    floatx4 acc[8][2];
    const floatx4 zero = {0.0f, 0.0f, 0.0f, 0.0f};
#pragma unroll
    for (int i = 0; i < 8; ++i)
#pragma unroll
        for (int j = 0; j < 2; ++j) acc[i][j] = zero;

    gemm256_mainloop<2>(A + z * sAz + (size_t)mbase * K,
                        B + z * sBz + (size_t)nbase * K, K, lds, acc);

    const int t = threadIdx.x, w = t >> 6, lane = t & 63;
    const int wm = w & 1, wn = w >> 1;
    const int r0 = mbase + wm * 128 + (lane >> 4) * 4;
    const int c0 = nbase + wn * 32 + (lane & 15);
    float* Cz = C + z * sCz;
#pragma unroll
    for (int i = 0; i < 8; ++i)
#pragma unroll
        for (int j = 0; j < 2; ++j)
#pragma unroll
            for (int r = 0; r < 4; ++r)
                Cz[(size_t)(r0 + i * 16 + r) * N + (c0 + j * 16)] = acc[i][j][r];
}

// ---------------------------------------------------------------------------
// In-place row softmax over 2048 bf16 logits. One block (256 thr) per row.
// ---------------------------------------------------------------------------
__global__ __launch_bounds__(256)
void softmax_rows_bf16(ushort* __restrict__ SP) {
    const int row = blockIdx.x;
    ushortx8* base = (ushortx8*)(SP + (size_t)row * 2048);
    const int t = threadIdx.x;
    const int w = t >> 6, lane = t & 63;
    ushortx8 v = base[t];
    float f[8];
#pragma unroll
    for (int k = 0; k < 8; ++k) f[k] = bf2f(v[k]);
    float m = f[0];
#pragma unroll
    for (int k = 1; k < 8; ++k) m = fmaxf(m, f[k]);
    for (int o = 32; o > 0; o >>= 1) m = fmaxf(m, __shfl_down(m, o));
    __shared__ float red[4];
    if (lane == 0) red[w] = m;
    __syncthreads();
    m = fmaxf(fmaxf(red[0], red[1]), fmaxf(red[2], red[3]));

    float e[8], s = 0.0f;
#pragma unroll
    for (int k = 0; k < 8; ++k) { e[k] = __expf(f[k] - m); s += e[k]; }
    for (int o = 32; o > 0; o >>= 1) s += __shfl_down(s, o);
    __syncthreads();
    if (lane == 0) red[w] = s;
    __syncthreads();
    float inv = 1.0f / (red[0] + red[1] + red[2] + red[3]);

    ushortx8 o;
#pragma unroll
    for (int k = 0; k < 8; ++k) o[k] = f2bf(e[k] * inv);
    base[t] = o;
}

// ---------------------------------------------------------------------------
// Merged fp32 -> bf16 cast for x | Wq | Wk | Wv (contiguous dst region).
// ---------------------------------------------------------------------------
__global__ __launch_bounds__(256)
void cast_bf16_all(const float* __restrict__ x, const float* __restrict__ Wq,
                   const float* __restrict__ Wk, const float* __restrict__ Wv,
                   ushort* __restrict__ dst) {
    const int NX = 2097152;   // 8192*1024/4
    const int NW = 262144;    // 1024*1024/4
    int i = blockIdx.x * 256 + threadIdx.x;
    const float* src;
    int off;
    if (i < NX)               { src = x;  off = 0; }
    else if (i < NX + NW)     { src = Wq; off = NX; }
    else if (i < NX + 2 * NW) { src = Wk; off = NX + NW; }
    else                      { src = Wv; off = NX + 2 * NW; }
    float4 v = ((const float4*)src)[i - off];
    ushortx4 o = {f2bf(v.x), f2bf(v.y), f2bf(v.z), f2bf(v.w)};
    ((ushortx4*)dst)[i] = o;
}

extern "C" void kernel_launch(void* const* d_in, const int* in_sizes, int n_in,
                              void* d_out, int out_size, void* d_ws, size_t ws_size,
                              hipStream_t stream) {
    const float* x  = (const float*)d_in[0];
    const float* bq = (const float*)d_in[2];
    const float* bk = (const float*)d_in[4];
    const float* bv = (const float*)d_in[6];
    float* out = (float*)d_out;

    const size_t R = 8192;   // B*S
    const size_t D = 1024;
    const size_t S = 2048;

    // ws layout (elems): xb R*D | Wb 3*D*D | Qs R*D | Ks R*D | Vt R*D | Sb 4*S*S(bf16)
    const size_t need = (4 * R * D + 3 * D * D + 4 * S * S) * 2;
    if (ws_size < need) return;

    ushort* xb = (ushort*)d_ws;
    ushort* Wb = xb + R * D;
    ushort* Qs = Wb + 3 * D * D;
    ushort* Ks = Qs + R * D;
    ushort* Vt = Ks + R * D;
    ushort* Sb = Vt + R * D;   // S scores, then P in place (bf16)

    cast_bf16_all<<<dim3(11264), dim3(256), 0, stream>>>(
        x, (const float*)d_in[1], (const float*)d_in[3], (const float*)d_in[5], xb);

    // QKV: one GEMM M=8192 N=3072 K=1024; BN=192 -> 512 blocks = 2 full rounds
    qkv_gemm<<<dim3(16, 32), dim3(512), 0, stream>>>(xb, Wb, bq, bk, bv, Qs, Ks, Vt);

    // S = Qs @ K^T per batch: M=N=2048, K=1024 (scale folded into Qs), bf16 out
    gemm_bt_bf16<<<dim3(8, 8, 4), dim3(512), 0, stream>>>(Qs, S * D, Ks, S * D, Sb, S * S,
                                                          (int)S, (int)D);

    // softmax rows in place -> bf16 P
    softmax_rows_bf16<<<dim3((unsigned)(4 * S)), dim3(256), 0, stream>>>(Sb);

    // O = P @ Vt^T per batch: M=2048, N=1024, K=2048
    gemm_bt_f32<<<dim3(8, 8, 4), dim3(512), 0, stream>>>(Sb, S * S, Vt, D * S, out, S * D,
                                                         (int)D, (int)S);
}